// Round 9
// baseline (415.546 us; speedup 1.0000x reference)
//
#include <hip/hip_runtime.h>
#include <cstdint>

// BFP quantize: block = channel vector at each (n,h,w), NCHW layout.
// N=64, C=256, H=W=56, mantissa_bits=3.
// delta = 2^(e-3), max_abs = m*2^e, m in [0.5,1) (frexp). q = trunc(x/delta)*delta.
// Exact pow2 arithmetic — absmax==0 verified R1..R8.
//
// R9: 256B-granule law (empirical, R1..R8): per-wave contiguous chunks must be
// >=256B for 1.0x HBM traffic. 1024B (R1) and 256B (R7) measured FETCH=1.000x;
// 128B (R8) -> 3.0x, 64B (R2/R5) -> 2.9x. So: wave = 16 sites (j=l&15,
// 16 x float4 = 256B aligned; HW4=784=16*49) x 4 channel-groups (g=l>>4).
// Lane sweeps 64 channels c=g+4i; 2-step butterfly (masks 16,32) closes all
// 256 channels in-wave. float4 loads (1KB/instr per outstanding slot — R7's
// 256B scalar loads were latency-starved at 3.5 TB/s). Two-sweep, pass B
// re-reads from L3 (R7: FETCH exactly 1.000x at this same wave count /
// residency). No LDS, no barriers. 3136 waves = 12.25/CU, fully resident.

constexpr int C      = 256;
constexpr int HW     = 56 * 56;    // 3136
constexpr int HW4    = HW / 4;     // 784 float4 per (n,c) plane (= 16*49)
constexpr int CHW4   = C * HW4;    // float4 per image
constexpr int CSTEP  = 4 * HW4;    // +4 channels, in float4 units

__device__ __forceinline__ int fexp(float x) {
    int e;
    (void)frexpf(x, &e);           // v_frexp_exp_i32_f32; e=0 for x==0
    return e;
}

__device__ __forceinline__ void fmax4(float4& m, const float4& v) {
    m.x = fmaxf(m.x, fabsf(v.x));
    m.y = fmaxf(m.y, fabsf(v.y));
    m.z = fmaxf(m.z, fabsf(v.z));
    m.w = fmaxf(m.w, fabsf(v.w));
}

__global__ __launch_bounds__(256, 8)
void bfp_kernel(const float4* __restrict__ in, float4* __restrict__ out) {
    const int l  = threadIdx.x & 63;
    const int w  = threadIdx.x >> 6;
    const int j  = l & 15;                // site within the wave's 256B chunk
    const int g  = l >> 4;                // channel group 0..3
    const int sg = blockIdx.x * 4 + w;    // 16-site group id (0..3135, exact)

    const int s  = sg * 16 + j;           // float4 site; groups never straddle
    const int n  = s / HW4;               //   channel planes (HW4 % 16 == 0)
    const int s4 = s - n * HW4;

    const float4* p = in  + (size_t)n * CHW4 + (size_t)g * HW4 + s4;
    float4*       q = out + (size_t)n * CHW4 + (size_t)g * HW4 + s4;

    // ---- pass A: abs-max over this lane's 64 channels (c = g + 4i) ----
    float4 a0 = make_float4(0.f, 0.f, 0.f, 0.f), a1 = a0, a2 = a0, a3 = a0;
#pragma unroll
    for (int i = 0; i < 64; i += 8) {
        float4 x0 = p[(i + 0) * CSTEP], x1 = p[(i + 1) * CSTEP];
        float4 x2 = p[(i + 2) * CSTEP], x3 = p[(i + 3) * CSTEP];
        float4 x4 = p[(i + 4) * CSTEP], x5 = p[(i + 5) * CSTEP];
        float4 x6 = p[(i + 6) * CSTEP], x7 = p[(i + 7) * CSTEP];
        fmax4(a0, x0); fmax4(a1, x1); fmax4(a2, x2); fmax4(a3, x3);
        fmax4(a0, x4); fmax4(a1, x5); fmax4(a2, x6); fmax4(a3, x7);
    }
    float4 m;
    m.x = fmaxf(fmaxf(a0.x, a1.x), fmaxf(a2.x, a3.x));
    m.y = fmaxf(fmaxf(a0.y, a1.y), fmaxf(a2.y, a3.y));
    m.z = fmaxf(fmaxf(a0.z, a1.z), fmaxf(a2.z, a3.z));
    m.w = fmaxf(fmaxf(a0.w, a1.w), fmaxf(a2.w, a3.w));

    // ---- butterfly across the 4 channel-groups sharing site j (no LDS) ----
#pragma unroll
    for (int mask = 16; mask < 64; mask <<= 1) {
        m.x = fmaxf(m.x, __shfl_xor(m.x, mask));
        m.y = fmaxf(m.y, __shfl_xor(m.y, mask));
        m.z = fmaxf(m.z, __shfl_xor(m.z, mask));
        m.w = fmaxf(m.w, __shfl_xor(m.w, mask));
    }

    // ---- shared exponent -> delta = 2^(e-3), inv = 2^(3-e) (both exact) ----
    const int ex = fexp(m.x), ey = fexp(m.y), ez = fexp(m.z), ew = fexp(m.w);
    const float dx = ldexpf(1.f, ex - 3), ix = ldexpf(1.f, 3 - ex);
    const float dy = ldexpf(1.f, ey - 3), iy = ldexpf(1.f, 3 - ey);
    const float dz = ldexpf(1.f, ez - 3), iz = ldexpf(1.f, 3 - ez);
    const float dw = ldexpf(1.f, ew - 3), iw = ldexpf(1.f, 3 - ew);

    // ---- pass B: re-read (L3-hit, proven R7 at this residency), quantize ----
#pragma unroll
    for (int i = 0; i < 64; i += 8) {
        float4 v[8];
#pragma unroll
        for (int k = 0; k < 8; ++k) v[k] = p[(i + k) * CSTEP];
#pragma unroll
        for (int k = 0; k < 8; ++k) {
            float4 r;
            r.x = truncf(v[k].x * ix) * dx;
            r.y = truncf(v[k].y * iy) * dy;
            r.z = truncf(v[k].z * iz) * dz;
            r.w = truncf(v[k].w * iw) * dw;
            q[(i + k) * CSTEP] = r;
        }
    }
}

extern "C" void kernel_launch(void* const* d_in, const int* in_sizes, int n_in,
                              void* d_out, int out_size, void* d_ws, size_t ws_size,
                              hipStream_t stream) {
    const float* in = (const float*)d_in[0];
    float* out      = (float*)d_out;
    int total4 = in_sizes[0] / (4 * C);    // 50176 float4 sites
    int blocks = total4 / 64;              // 784 blocks (4 waves x 16 sites), exact
    bfp_kernel<<<blocks, 256, 0, stream>>>((const float4*)in, (float4*)out);
}

// Round 10
// 218.871 us; speedup vs baseline: 1.8986x; 1.8986x over previous
//
#include <hip/hip_runtime.h>
#include <cstdint>

// BFP quantize: block = channel vector at each (n,h,w), NCHW layout.
// N=64, C=256, H=W=56, mantissa_bits=3.
// delta = 2^(e-3), max_abs = m*2^e, m in [0.5,1) (frexp). q = trunc(x/delta)*delta.
// Exact pow2 arithmetic — absmax==0 verified R1..R9.
//
// R10: scatter law (R1..R9 counters): a wave instruction must be ONE
// contiguous run for 1.0x HBM traffic. R1 (1024B run) and R7 (256B run)
// measured FETCH/WRITE exactly 1.000x; ANY intra-instruction multi-chunk
// scatter (R9: 4x256B -> 3.6x; R8: 8x128B -> 3.0x; R2/R5: 16x64B -> 2.9x)
// amplifies ~3x regardless of chunk alignment. So channel-splitting goes
// ACROSS WAVES: R7's exact clean structure, but the 4 waves of a block split
// the 256 channels (wave w -> channels [w*64, w*64+64)) over a shared
// 64-scalar-site window, combined via 1KB LDS + one barrier.
// Waves: 200704/64 * 4 = 12544 = 49/CU work, 32/CU resident (~30 VGPR,
// 8/SIMD) vs R7's grid-capped 12.25 — the sole flaw R7 had.
// Window = 64 sites = 256B aligned run (HW=3136=49*64: no image straddle;
// plane stride 12544=49*256: aligned). Pass B re-reads the wave's OWN
// channels (tighter reuse than R7's proven L3-hit) and stores clean.

constexpr int C   = 256;
constexpr int HW  = 56 * 56;     // 3136 = 49 * 64
constexpr int CHW = C * HW;      // 802816
constexpr int WCH = 64;          // channels per wave (4 waves cover C)
constexpr int WPI = HW / 64;     // 49 site-windows per image

__device__ __forceinline__ int fexp(float x) {
    int e;
    (void)frexpf(x, &e);         // v_frexp_exp_i32_f32; e=0 for x==0
    return e;
}

__global__ __launch_bounds__(256, 8)
void bfp_kernel(const float* __restrict__ in, float* __restrict__ out) {
    const int l   = threadIdx.x & 63;    // lane = site within window
    const int w   = threadIdx.x >> 6;    // wave = channel quarter
    const int win = blockIdx.x;          // 3136 windows of 64 scalar sites
    const int n   = win / WPI;           // image
    const int r   = (win - n * WPI) * 64 + l;   // scalar site within image

    const float* p = in  + (size_t)n * CHW + (size_t)w * WCH * HW + r;
    float*       q = out + (size_t)n * CHW + (size_t)w * WCH * HW + r;

    // ---- pass A: abs-max over this wave's 64 channels at site r ----
    // (each instruction: 64 lanes x 4B = ONE contiguous 256B run at channel c)
    float m0 = 0.f, m1 = 0.f, m2 = 0.f, m3 = 0.f;
#pragma unroll
    for (int c = 0; c < WCH; c += 16) {
        float x0 = p[(c +  0) * HW], x1 = p[(c +  1) * HW];
        float x2 = p[(c +  2) * HW], x3 = p[(c +  3) * HW];
        float x4 = p[(c +  4) * HW], x5 = p[(c +  5) * HW];
        float x6 = p[(c +  6) * HW], x7 = p[(c +  7) * HW];
        float x8 = p[(c +  8) * HW], x9 = p[(c +  9) * HW];
        float xa = p[(c + 10) * HW], xb = p[(c + 11) * HW];
        float xc = p[(c + 12) * HW], xd = p[(c + 13) * HW];
        float xe = p[(c + 14) * HW], xf = p[(c + 15) * HW];
        m0 = fmaxf(m0, fabsf(x0)); m1 = fmaxf(m1, fabsf(x1));
        m2 = fmaxf(m2, fabsf(x2)); m3 = fmaxf(m3, fabsf(x3));
        m0 = fmaxf(m0, fabsf(x4)); m1 = fmaxf(m1, fabsf(x5));
        m2 = fmaxf(m2, fabsf(x6)); m3 = fmaxf(m3, fabsf(x7));
        m0 = fmaxf(m0, fabsf(x8)); m1 = fmaxf(m1, fabsf(x9));
        m2 = fmaxf(m2, fabsf(xa)); m3 = fmaxf(m3, fabsf(xb));
        m0 = fmaxf(m0, fabsf(xc)); m1 = fmaxf(m1, fabsf(xd));
        m2 = fmaxf(m2, fabsf(xe)); m3 = fmaxf(m3, fabsf(xf));
    }
    float m = fmaxf(fmaxf(m0, m1), fmaxf(m2, m3));

    // ---- cross-wave combine: 1KB LDS, one barrier ----
    __shared__ float red[4][64];
    red[w][l] = m;
    __syncthreads();
    m = fmaxf(fmaxf(red[0][l], red[1][l]), fmaxf(red[2][l], red[3][l]));

    // ---- shared exponent -> delta = 2^(e-3), inv = 2^(3-e) (both exact) ----
    const int   e  = fexp(m);
    const float dq = ldexpf(1.f, e - 3);
    const float iq = ldexpf(1.f, 3 - e);

    // ---- pass B: re-read own channels (L3-hit, proven R7), quantize, store ----
#pragma unroll
    for (int c = 0; c < WCH; c += 8) {
        float v[8];
#pragma unroll
        for (int k = 0; k < 8; ++k) v[k] = p[(c + k) * HW];
#pragma unroll
        for (int k = 0; k < 8; ++k) q[(c + k) * HW] = truncf(v[k] * iq) * dq;
    }
}

extern "C" void kernel_launch(void* const* d_in, const int* in_sizes, int n_in,
                              void* d_out, int out_size, void* d_ws, size_t ws_size,
                              hipStream_t stream) {
    const float* in = (const float*)d_in[0];
    float* out      = (float*)d_out;
    int windows = in_sizes[0] / (C * 64);   // 3136 blocks (64-site windows)
    bfp_kernel<<<windows, 256, 0, stream>>>(in, out);
}